// Round 7
// baseline (2111.687 us; speedup 1.0000x reference)
//
#include <hip/hip_runtime.h>
#include <hip/hip_cooperative_groups.h>
#include <stdint.h>
namespace cg = cooperative_groups;

// ---------------- problem constants ----------------
constexpr int N_   = 20000;
constexpr int E_   = 160000;
constexpr int C_   = 64;
constexpr int K_   = 2000;
constexpr int EV_  = 32000;
constexpr int EALL_ = E_ + EV_;          // 192000
constexpr int CSH_ = 576;                // C*SH
constexpr int TB_  = 48;                 // edges per block in batched conv
constexpr int GRID_ = 768;               // 3 blocks/CU x 256 CU (cooperative co-residency)
constexpr int NTILE_ = (K_ / 16) * (K_ / 16);   // 15625
constexpr int SPAN_ = 27;                // ceil(N/GRID) for the scan stage

// ---------------- workspace layout (bytes) ----------------
// [ zero region: [0, OFF_STATE) zeroed grid-wide; state zeroed by last block ]
constexpr size_t OFF_AGG    = 0;                  // N*C f32
constexpr size_t OFF_DEG    = 5120000;            // N f32
constexpr size_t OFF_AGGM   = 5200000;            // K*C f32
constexpr size_t OFF_DEGM   = 5712000;            // K f32
constexpr size_t OFF_RANK   = 5720000;            // N i32
constexpr size_t OFF_MASKA  = 5800000;            // EALL f32
constexpr size_t OFF_EXIST  = 6568000;            // K*K u8
constexpr size_t OFF_HIST   = 10568000;           // 1024 u32
constexpr size_t OFF_BSUM   = 10572096;           // GRID i32 (block sel counts)
constexpr size_t OFF_BBASE  = 10575168;           // GRID i32 (exclusive bases)
constexpr size_t OFF_STATE  = 10578240;           // RState + counters (256 B)
constexpr size_t ZERO_MAIN  = OFF_STATE;
// [ non-zero region ]
constexpr size_t OFF_HLOCAL = 10578496;           // N*C f32
constexpr size_t OFF_KEY    = 15698496;           // N u64
constexpr size_t OFF_SCORE  = 15858496;           // N f32
constexpr size_t OFF_N2M    = 15938496;           // N i32
constexpr size_t OFF_MIDX   = 16018496;           // K i32
constexpr size_t OFF_HM     = 16026496;           // K*C f32
constexpr size_t OFF_POSM   = 16538496;           // K*3 f32
constexpr size_t OFF_Q      = 16562496;           // K*16 f32
constexpr size_t OFF_KBUF   = 16690496;           // K*16 f32
constexpr size_t OFF_SRCA   = 16818496;           // EALL i32
constexpr size_t OFF_DSTA   = 17586496;           // EALL i32
constexpr size_t OFF_TMAX   = 18354496;           // 15625 f32 (+pad)
constexpr size_t OFF_CAND   = 18417024;           // 32 MB: cand keys / edata overlay
// total ~50.42 MB

struct RState {
    unsigned long long prefix;
    int R;
    unsigned int cand_count;
    unsigned int sel_count;
    int bin_thresh;
    unsigned int total;
    unsigned int pad;
};
// state area: RState at +0, cnt0 at +64, cnt1 at +68, w0nz at +72

struct P {
    const float* h; const float* pos; const int* eidx;
    const float* fc_w1; const float* fc_b1; const float* fc_w2; const float* fc_b2;
    const float* lin_w; const float* ms_w1; const float* ms_b1; const float* ms_w2;
    const float* ms_b2; const float* vg_wq; const float* vg_wk;
    char* ws;
    float* out_h; float* out_pos; float* out_av; float* out_m;
};

constexpr int SMEM_BYTES = 44800;

// ================= stage device functions =================

// ---- stage 0: zero workspace + (last block) compute w0nz ----
__device__ void st0_init(const P& p, char* smem)
{
    float4 zero4 = make_float4(0.f, 0.f, 0.f, 0.f);
    float4* z = (float4*)p.ws;
    int nz4 = (int)(ZERO_MAIN / 16);
    for (int i = blockIdx.x * 256 + threadIdx.x; i < nz4; i += GRID_ * 256) z[i] = zero4;
    if (blockIdx.x == GRID_ - 1) {
        int t = threadIdx.x;
        float4* zs = (float4*)(p.ws + OFF_STATE);
        if (t < 16) zs[t] = zero4;
        float* hid0 = (float*)smem;
        int* nz = (int*)(smem + 256);
        if (t == 0) *nz = 0;
        if (t < 64) hid0[t] = fmaxf(p.fc_b1[t], 0.0f);
        __syncthreads();
        for (int j = t; j < CSH_; j += 256) {
            float acc = p.fc_b2[j];
            for (int k = 0; k < 64; k++) acc += hid0[k] * p.fc_w2[k * CSH_ + j];
            if (acc != 0.0f) atomicOr(nz, 1);
        }
        __syncthreads();
        if (t == 0) *(int*)(p.ws + OFF_STATE + 72) = *nz;
    }
}

// ---- edge prep (shared by conv1/conv2): geometry + bessel + deg + compaction ----
__device__ void prep_stage(const P& p, int n_edges, const int* __restrict__ src,
    const int* __restrict__ dst, const float* __restrict__ mask,
    const float* __restrict__ posn, float* __restrict__ deg,
    float* __restrict__ edata, unsigned int* __restrict__ cnt)
{
    int w0flag = *(const int*)(p.ws + OFF_STATE + 72);
    int e = blockIdx.x * 256 + threadIdx.x;
    bool valid = e < n_edges;
    int s_i = 0, d_i = 0; float msk = 0.0f;
    if (valid) {
        msk = mask ? mask[e] : 1.0f;
        if (msk != 0.0f) { s_i = src[e]; d_i = dst[e]; }
    }
    bool active = valid && (msk != 0.0f);

    float vx = 0.f, vy = 0.f, vz = 0.f;
    if (active) {
        vx = posn[s_i*3+0] - posn[d_i*3+0];
        vy = posn[s_i*3+1] - posn[d_i*3+1];
        vz = posn[s_i*3+2] - posn[d_i*3+2];
    }
    float r = sqrtf(vx*vx + vy*vy + vz*vz + 1e-12f);
    float invr = 1.0f / r;
    float x = vx*invr, y = vy*invr, z = vz*invr;
    const float s3 = 1.7320508075688772f, s15 = 3.872983346207417f, s5 = 2.23606797749979f;
    float sh[9];
    sh[0] = 1.0f; sh[1] = s3*x; sh[2] = s3*y; sh[3] = s3*z;
    sh[4] = s15*x*y; sh[5] = s15*y*z; sh[6] = 0.5f*s5*(3.0f*z*z - 1.0f);
    sh[7] = s15*x*z; sh[8] = 0.5f*s15*(x*x - y*y);

    float u = r * 0.2f; u = u > 1.0f ? 1.0f : u;
    float u2 = u*u, u6 = u2*u2*u2, u7 = u6*u, u8 = u7*u;
    float env = 1.0f - 28.0f*u6 + 48.0f*u7 - 21.0f*u8;
    float rc = r > 1e-9f ? r : 1e-9f;
    const float bpref = 0.6324555320336759f;      // sqrt(2/5)
    const float PIov5 = 0.6283185307179586f;
    float ef[8];
    #pragma unroll
    for (int n = 0; n < 8; n++)
        ef[n] = bpref * sinf(PIov5 * r * (float)(n + 1)) / rc * env;

    if (active) atomicAdd(&deg[s_i], msk);

    bool contrib = active && !((env == 0.0f) && (w0flag == 0));
    int lane = threadIdx.x & 63;
    unsigned long long b = __ballot(contrib);
    int wc = __popcll(b);
    int base = 0;
    if (lane == 0 && wc) base = (int)atomicAdd(cnt, (unsigned)wc);
    base = __shfl(base, 0);
    if (contrib) {
        int slot = base + __popcll(b & ((1ull << lane) - 1ull));
        float* pp = edata + (size_t)slot * 20;
        #pragma unroll
        for (int n = 0; n < 8; n++) pp[n] = ef[n];
        #pragma unroll
        for (int t = 0; t < 9; t++) pp[8+t] = sh[t];
        pp[17] = __int_as_float(s_i);
        pp[18] = __int_as_float(d_i);
        pp[19] = msk;
    }
}

// ---- batched conv GEMM (R6 structure; LDS carve) ----
__device__ void st_conv(const P& p, char* smem, const unsigned int* __restrict__ cnt,
    const float* __restrict__ edata, const float* __restrict__ hn, float* __restrict__ agg)
{
    float* s_misc = (float*)smem;                  // 2304 B
    float* s_hid  = (float*)(smem + 2304);         // 13056 B
    float* s_tp   = (float*)(smem + 15360);        // 13056 B
    float* s_w    = (float*)(smem + 28416);        // 16384 B

    const int tid = threadIdx.x;
    const int oq = (tid & 15) * 4;
    const int eg = tid >> 4;

    const int nheavy = (int)*cnt;
    const int nblk = (nheavy + TB_ - 1) / TB_;

    for (int blk = blockIdx.x; blk < nblk; blk += GRID_) {
        const int ebase = blk * TB_;
        int nE = nheavy - ebase; if (nE > TB_) nE = TB_;

        __syncthreads();
        for (int idx = tid; idx < TB_ * 12; idx += 256) {
            int e = idx / 12, f = idx - 12 * e;
            float v = 0.0f;
            if (e < nE) {
                const float* pp = edata + (size_t)(ebase + e) * 20;
                v = (f < 9) ? pp[8 + f] : (f == 9) ? pp[17] : (f == 10) ? pp[19] : pp[18];
            }
            s_misc[idx] = v;
        }
        for (int idx = tid; idx < TB_ * 64; idx += 256) {
            int e = idx >> 6, k = idx & 63;
            float hv = 0.0f;
            if (e < nE) {
                const float* pp = edata + (size_t)(ebase + e) * 20;
                float acc = p.fc_b1[k];
                #pragma unroll
                for (int n = 0; n < 8; n++) acc += pp[n] * p.fc_w1[n * 64 + k];
                hv = fmaxf(acc, 0.0f);
            }
            s_hid[e * 68 + k] = hv;
        }
        float acc0[4] = {0,0,0,0}, acc1[4] = {0,0,0,0}, acc2[4] = {0,0,0,0};
        __syncthreads();

        const int d0 = __float_as_int(s_misc[eg * 12 + 11]);
        const int d1 = __float_as_int(s_misc[(eg + 16) * 12 + 11]);
        const int d2 = __float_as_int(s_misc[(eg + 32) * 12 + 11]);

        for (int cj = 0; cj < 9; cj++) {
            const int j0 = cj * 64;
            if (cj) __syncthreads();
            for (int i4 = tid; i4 < 1024; i4 += 256) {
                int k = i4 >> 4, q4 = (i4 & 15) * 4;
                *reinterpret_cast<float4*>(&s_w[k * 64 + q4]) =
                    *reinterpret_cast<const float4*>(&p.fc_w2[k * CSH_ + j0 + q4]);
            }
            __syncthreads();

            const int jb = j0 + oq;
            const int c0 = jb / 9, c1 = (jb + 3) / 9;
            float hA0 = hn[d0 * 64 + c0], hB0 = hn[d0 * 64 + c1];
            float hA1 = hn[d1 * 64 + c0], hB1 = hn[d1 * 64 + c1];
            float hA2 = hn[d2 * 64 + c0], hB2 = hn[d2 * 64 + c1];

            float a0[4], a1[4], a2[4];
            #pragma unroll
            for (int q = 0; q < 4; q++) { float b = p.fc_b2[jb + q]; a0[q]=b; a1[q]=b; a2[q]=b; }
            #pragma unroll 4
            for (int k = 0; k < 64; k++) {
                float4 w4 = *reinterpret_cast<const float4*>(&s_w[k * 64 + oq]);
                float h0 = s_hid[eg * 68 + k];
                float h1 = s_hid[(eg + 16) * 68 + k];
                float h2 = s_hid[(eg + 32) * 68 + k];
                a0[0]+=h0*w4.x; a0[1]+=h0*w4.y; a0[2]+=h0*w4.z; a0[3]+=h0*w4.w;
                a1[0]+=h1*w4.x; a1[1]+=h1*w4.y; a1[2]+=h1*w4.z; a1[3]+=h1*w4.w;
                a2[0]+=h2*w4.x; a2[1]+=h2*w4.y; a2[2]+=h2*w4.z; a2[3]+=h2*w4.w;
            }
            #pragma unroll
            for (int q = 0; q < 4; q++) {
                int j = jb + q; int cc = j / 9; int si = j - 9 * cc;
                s_tp[eg * 68 + oq + q]        = (cc == c0 ? hA0 : hB0) * s_misc[eg * 12 + si]        * a0[q];
                s_tp[(eg + 16) * 68 + oq + q] = (cc == c0 ? hA1 : hB1) * s_misc[(eg + 16) * 12 + si] * a1[q];
                s_tp[(eg + 32) * 68 + oq + q] = (cc == c0 ? hA2 : hB2) * s_misc[(eg + 32) * 12 + si] * a2[q];
            }
            __syncthreads();

            for (int i4 = tid; i4 < 1024; i4 += 256) {
                *reinterpret_cast<float4*>(&s_w[i4 * 4]) =
                    *reinterpret_cast<const float4*>(&p.lin_w[j0 * 64 + i4 * 4]);
            }
            __syncthreads();

            #pragma unroll 4
            for (int jj = 0; jj < 64; jj++) {
                float4 l4 = *reinterpret_cast<const float4*>(&s_w[jj * 64 + oq]);
                float t0 = s_tp[eg * 68 + jj];
                float t1 = s_tp[(eg + 16) * 68 + jj];
                float t2 = s_tp[(eg + 32) * 68 + jj];
                acc0[0]+=t0*l4.x; acc0[1]+=t0*l4.y; acc0[2]+=t0*l4.z; acc0[3]+=t0*l4.w;
                acc1[0]+=t1*l4.x; acc1[1]+=t1*l4.y; acc1[2]+=t1*l4.z; acc1[3]+=t1*l4.w;
                acc2[0]+=t2*l4.x; acc2[1]+=t2*l4.y; acc2[2]+=t2*l4.z; acc2[3]+=t2*l4.w;
            }
        }

        {
            float mk = s_misc[eg * 12 + 10];
            if (mk != 0.0f) {
                int s = __float_as_int(s_misc[eg * 12 + 9]);
                #pragma unroll
                for (int q = 0; q < 4; q++) atomicAdd(&agg[s * 64 + oq + q], acc0[q] * mk);
            }
            mk = s_misc[(eg + 16) * 12 + 10];
            if (mk != 0.0f) {
                int s = __float_as_int(s_misc[(eg + 16) * 12 + 9]);
                #pragma unroll
                for (int q = 0; q < 4; q++) atomicAdd(&agg[s * 64 + oq + q], acc1[q] * mk);
            }
            mk = s_misc[(eg + 32) * 12 + 10];
            if (mk != 0.0f) {
                int s = __float_as_int(s_misc[(eg + 32) * 12 + 9]);
                #pragma unroll
                for (int q = 0; q < 4; q++) atomicAdd(&agg[s * 64 + oq + q], acc2[q] * mk);
            }
        }
    }
}

// ---- stage 3: h_local + score + key ----
__device__ void st3_hlscore(const P& p)
{
    const float* agg = (const float*)(p.ws + OFF_AGG);
    const float* deg = (const float*)(p.ws + OFF_DEG);
    float* h_local = (float*)(p.ws + OFF_HLOCAL);
    float* score = (float*)(p.ws + OFF_SCORE);
    unsigned long long* key = (unsigned long long*)(p.ws + OFF_KEY);
    int lane = threadIdx.x & 63;
    int gw = (blockIdx.x * 256 + threadIdx.x) >> 6;
    for (int n = gw; n < N_; n += GRID_ * 4) {
        float d = fmaxf(deg[n], 1.0f);
        float hl = p.h[n*64 + lane] + agg[n*64 + lane] / d;
        h_local[n*64 + lane] = hl;
        float acc = p.ms_b1[lane];
        #pragma unroll
        for (int i = 0; i < 16; i++) acc += __shfl(hl, i) * p.ms_w1[i*64 + lane];
        acc = fmaxf(acc, 0.0f);
        float part = acc * p.ms_w2[lane];
        #pragma unroll
        for (int off = 32; off > 0; off >>= 1) part += __shfl_xor(part, off);
        if (lane == 0) {
            float s = part + p.ms_b2[0];
            float sc = 1.0f / (1.0f + expf(-s));
            score[n] = sc;
            key[n] = ((unsigned long long)__float_as_uint(sc) << 32)
                   | (unsigned long long)(0xFFFFFFFFu - (unsigned)n);
        }
    }
}

// ---- stage 4: rank counting ----
__device__ void st4_rank(const P& p)
{
    const unsigned long long* key = (const unsigned long long*)(p.ws + OFF_KEY);
    int* rankcnt = (int*)(p.ws + OFF_RANK);
    int tid = threadIdx.x;
    for (int unit = blockIdx.x; unit < 79 * 16; unit += GRID_) {
        int i = (unit % 79) * 256 + tid;
        int seg = unit / 79;
        int lo = seg * 1250, hi = lo + 1250;
        unsigned long long my = (i < N_) ? key[i] : ~0ull;
        int cnt = 0;
        #pragma unroll 8
        for (int j = lo; j < hi; j++) cnt += (key[j] > my) ? 1 : 0;
        if (i < N_ && cnt) atomicAdd(&rankcnt[i], cnt);
    }
}

// ---- stage 5: selection scan (3 phases) ----
__device__ void st5a_count(const P& p)
{
    const int* rankcnt = (const int*)(p.ws + OFF_RANK);
    const float* score = (const float*)(p.ws + OFF_SCORE);
    int* bsum = (int*)(p.ws + OFF_BSUM);
    if (threadIdx.x < 64) {
        int lane = threadIdx.x;
        int idx = blockIdx.x * SPAN_ + lane;
        bool in = (lane < SPAN_) && (idx < N_);
        int sel = 0;
        if (in) {
            sel = (rankcnt[idx] < K_) ? 1 : 0;
            p.out_m[idx] = sel ? score[idx] : 0.0f;
        }
        unsigned long long bal = __ballot(sel);
        if (lane == 0) bsum[blockIdx.x] = __popcll(bal);
    }
}

__device__ void st5b_base(const P& p, char* smem)      // block 0 only
{
    int* bsum = (int*)(p.ws + OFF_BSUM);
    int* bbase = (int*)(p.ws + OFF_BBASE);
    int t = threadIdx.x, lane = t & 63, wv = t >> 6;
    int a0 = bsum[3*t], a1 = bsum[3*t+1], a2 = bsum[3*t+2];
    int local = a0 + a1 + a2;
    int v = local;
    #pragma unroll
    for (int off = 1; off < 64; off <<= 1) {
        int u = __shfl_up(v, off);
        if (lane >= off) v += u;
    }
    int* wsums = (int*)smem;
    if (lane == 63) wsums[wv] = v;
    __syncthreads();
    if (t == 0) { int run = 0; for (int w = 0; w < 4; w++) { int c = wsums[w]; wsums[w] = run; run += c; } }
    __syncthreads();
    int excl = wsums[wv] + v - local;
    bbase[3*t] = excl; bbase[3*t+1] = excl + a0; bbase[3*t+2] = excl + a0 + a1;
}

__device__ void st5c_emitmap(const P& p)
{
    const int* rankcnt = (const int*)(p.ws + OFF_RANK);
    const int* bbase = (const int*)(p.ws + OFF_BBASE);
    int* node2m = (int*)(p.ws + OFF_N2M);
    int* midx = (int*)(p.ws + OFF_MIDX);
    if (threadIdx.x < 64) {
        int lane = threadIdx.x;
        int idx = blockIdx.x * SPAN_ + lane;
        bool in = (lane < SPAN_) && (idx < N_);
        int sel = in ? ((rankcnt[idx] < K_) ? 1 : 0) : 0;
        unsigned long long bal = __ballot(sel);
        int pre = __popcll(bal & ((1ull << lane) - 1ull));
        if (in) {
            if (sel) { int rk = bbase[blockIdx.x] + pre; node2m[idx] = rk; midx[rk] = idx; }
            else node2m[idx] = -1;
        }
    }
}

// ---- stage 6: master gather + q/k proj + exist ----
__device__ void st6_mastex(const P& p)
{
    const int* midx = (const int*)(p.ws + OFF_MIDX);
    const float* h_local = (const float*)(p.ws + OFF_HLOCAL);
    const int* node2m = (const int*)(p.ws + OFF_N2M);
    float* h_m = (float*)(p.ws + OFF_HM);
    float* pos_m = (float*)(p.ws + OFF_POSM);
    float* qbuf = (float*)(p.ws + OFF_Q);
    float* kbuf = (float*)(p.ws + OFF_KBUF);
    int* src_all = (int*)(p.ws + OFF_SRCA);
    int* dst_all = (int*)(p.ws + OFF_DSTA);
    float* mask_all = (float*)(p.ws + OFF_MASKA);
    unsigned char* exist = (unsigned char*)(p.ws + OFF_EXIST);
    const int* src = p.eidx; const int* dst = p.eidx + E_;

    int lane = threadIdx.x & 63;
    int gw = (blockIdx.x * 256 + threadIdx.x) >> 6;
    for (int mi = gw; mi < K_; mi += GRID_ * 4) {
        int node = midx[mi];
        h_m[mi*64 + lane] = h_local[node*64 + lane];
        if (lane < 3) pos_m[mi*3 + lane] = p.pos[node*3 + lane];
        if (lane < 32) {
            int j = lane & 15;
            const float* wm = (lane < 16) ? p.vg_wq : p.vg_wk;
            float acc = 0.0f;
            #pragma unroll
            for (int i = 0; i < 16; i++) acc += h_local[node*64 + i] * wm[i*16 + j];
            if (lane < 16) qbuf[mi*16 + j] = acc; else kbuf[mi*16 + j] = acc;
        }
    }
    for (int e = blockIdx.x * 256 + threadIdx.x; e < E_; e += GRID_ * 256) {
        int sm = node2m[src[e]], dm = node2m[dst[e]];
        bool em = (sm >= 0) && (dm >= 0);
        int smc = sm >= 0 ? sm : 0;
        int dmc = dm >= 0 ? dm : 0;
        src_all[e] = smc; dst_all[e] = dmc; mask_all[e] = em ? 1.0f : 0.0f;
        if (em) exist[smc * K_ + dmc] = 1;
    }
}

// ---- stage 7a: attention pass 1 (Av + tile max + histogram) ----
__device__ void st7a_attn1(const P& p, char* smem)
{
    const float* qbuf = (const float*)(p.ws + OFF_Q);
    const float* kbuf = (const float*)(p.ws + OFF_KBUF);
    const unsigned char* exist = (const unsigned char*)(p.ws + OFF_EXIST);
    float* tmax = (float*)(p.ws + OFF_TMAX);
    unsigned int* hist = (unsigned int*)(p.ws + OFF_HIST);
    float (*sq)[17] = (float(*)[17])smem;
    float (*sk)[17] = (float(*)[17])(smem + 1088);
    unsigned int* lh = (unsigned int*)(smem + 2176);
    float* wmax = (float*)(smem + 6272);
    constexpr int TBK = K_ / 16;
    int tid = threadIdx.x;
    for (int b = tid; b < 1024; b += 256) lh[b] = 0;

    for (int t = blockIdx.x; t < NTILE_; t += GRID_) {
        int bi = t / TBK, bj = t % TBK;
        int i0 = bi * 16, j0 = bj * 16;
        int r = tid >> 4, c = tid & 15;
        __syncthreads();
        sq[r][c] = qbuf[(i0 + r) * 16 + c];
        sk[r][c] = kbuf[(j0 + r) * 16 + c];
        __syncthreads();
        int ti = tid >> 4, tj = tid & 15;
        float dot = 0.0f;
        #pragma unroll
        for (int cc = 0; cc < 16; cc++) dot += sq[ti][cc] * sk[tj][cc];
        float attn = 1.0f / (1.0f + expf(-dot * 0.25f));
        int gi = i0 + ti, gj = j0 + tj;
        int flat = gi * K_ + gj;
        bool ex = (exist[flat] != 0) || (gi == gj);
        bool av = (!ex) && (attn > 0.5f);
        p.out_av[flat] = av ? 1.0f : 0.0f;
        float cv = av ? attn : 0.0f;
        if (av) {
            unsigned bin = (__float_as_uint(attn) - 0x3F000000u) >> 13;
            if (bin > 1023u) bin = 1023u;
            atomicAdd(&lh[bin], 1u);
        }
        float wm = cv;
        #pragma unroll
        for (int off = 32; off > 0; off >>= 1) wm = fmaxf(wm, __shfl_xor(wm, off));
        int wid = tid >> 6, lane = tid & 63;
        if (lane == 0) wmax[wid] = wm;
        __syncthreads();
        if (tid == 0) tmax[t] = fmaxf(fmaxf(wmax[0], wmax[1]), fmaxf(wmax[2], wmax[3]));
    }
    __syncthreads();
    for (int b = tid; b < 1024; b += 256) {
        unsigned v = lh[b];
        if (v) atomicAdd(&hist[b], v);
    }
}

// ---- stage 7b: bin threshold pick (block 0) ----
__device__ void st7b_bsel(const P& p, char* smem)
{
    const unsigned int* hist = (const unsigned int*)(p.ws + OFF_HIST);
    RState* st = (RState*)(p.ws + OFF_STATE);
    unsigned int* ha = (unsigned int*)smem;
    unsigned int* hb = (unsigned int*)(smem + 4096);
    int tid = threadIdx.x;
    for (int b = tid; b < 1024; b += 256) ha[b] = hist[b];
    __syncthreads();
    unsigned* srcp = ha; unsigned* dstp = hb;
    for (int off = 1; off < 1024; off <<= 1) {
        for (int b = tid; b < 1024; b += 256)
            dstp[b] = srcp[b] + ((b + off < 1024) ? srcp[b + off] : 0u);
        __syncthreads();
        unsigned* tmp = srcp; srcp = dstp; dstp = tmp;
    }
    unsigned total = srcp[0];
    int R = (total < (unsigned)EV_) ? (int)total : EV_;
    if (tid == 0) {
        st->R = R; st->total = total; st->cand_count = 0; st->sel_count = 0;
        if (R == 0) st->bin_thresh = 1024;
    }
    __syncthreads();
    if (R > 0) {
        for (int b = tid; b < 1024; b += 256) {
            unsigned hi2 = (b == 1023) ? 0u : srcp[b + 1];
            if ((int)srcp[b] >= R && (int)hi2 < R) st->bin_thresh = b;
        }
    }
}

// ---- stage 8: attention pass 2 (store candidates) ----
__device__ void st8_attn2(const P& p, char* smem)
{
    const float* qbuf = (const float*)(p.ws + OFF_Q);
    const float* kbuf = (const float*)(p.ws + OFF_KBUF);
    const unsigned char* exist = (const unsigned char*)(p.ws + OFF_EXIST);
    const float* tmax = (const float*)(p.ws + OFF_TMAX);
    RState* st = (RState*)(p.ws + OFF_STATE);
    unsigned long long* cand = (unsigned long long*)(p.ws + OFF_CAND);
    float (*sq)[17] = (float(*)[17])smem;
    float (*sk)[17] = (float(*)[17])(smem + 1088);
    int* wb = (int*)(smem + 2176);
    int* bbp = (int*)(smem + 2192);
    constexpr int TBK = K_ / 16;
    int tid = threadIdx.x;
    unsigned tbits = 0x3F000000u + ((unsigned)st->bin_thresh << 13);

    for (int t = blockIdx.x; t < NTILE_; t += GRID_) {
        if (__float_as_uint(tmax[t]) < tbits) continue;     // block-uniform
        int bi = t / TBK, bj = t % TBK;
        int i0 = bi * 16, j0 = bj * 16;
        int r = tid >> 4, c = tid & 15;
        __syncthreads();
        sq[r][c] = qbuf[(i0 + r) * 16 + c];
        sk[r][c] = kbuf[(j0 + r) * 16 + c];
        __syncthreads();
        int ti = tid >> 4, tj = tid & 15;
        float dot = 0.0f;
        #pragma unroll
        for (int cc = 0; cc < 16; cc++) dot += sq[ti][cc] * sk[tj][cc];
        float attn = 1.0f / (1.0f + expf(-dot * 0.25f));
        int gi = i0 + ti, gj = j0 + tj;
        int flat = gi * K_ + gj;
        bool ex = (exist[flat] != 0) || (gi == gj);
        bool store = (!ex) && (attn > 0.5f) && (__float_as_uint(attn) >= tbits);

        unsigned long long keyv = ((unsigned long long)__float_as_uint(attn) << 32)
                                | (unsigned long long)(0xFFFFFFFFu - (unsigned)flat);
        int wid = tid >> 6, lane = tid & 63;
        unsigned long long b = __ballot(store);
        int wc = __popcll(b);
        if (lane == 0) wb[wid] = wc;
        __syncthreads();
        if (tid == 0) {
            int s = 0;
            for (int w = 0; w < 4; w++) { int cc2 = wb[w]; wb[w] = s; s += cc2; }
            *bbp = s ? (int)atomicAdd(&st->cand_count, (unsigned)s) : 0;
        }
        __syncthreads();
        if (store) {
            int slot = *bbp + wb[wid] + __popcll(b & ((1ull << lane) - 1ull));
            cand[slot] = keyv;
        }
    }
}

// ---- stage 9a: radix threshold (block 0, 3 passes + ties) ----
__device__ void st9a_radix(const P& p, char* smem)
{
    RState* st = (RState*)(p.ws + OFF_STATE);
    const unsigned long long* cand = (const unsigned long long*)(p.ws + OFF_CAND);
    unsigned int* s_tie = (unsigned int*)smem;              // 32768 B
    unsigned int* lh = (unsigned int*)(smem + 32768);       // 1024 B
    unsigned int* suf = (unsigned int*)(smem + 33792);      // 1024 B
    unsigned int* scal = (unsigned int*)(smem + 34816);     // s_pref, s_R, s_tiecnt, s_cfth
    int tid = threadIdx.x;
    int n = (int)st->cand_count;
    int R = st->R;
    if (tid == 0) { scal[0] = 0x3F000000u; scal[1] = (unsigned)R; scal[2] = 0; scal[3] = 0; }
    __syncthreads();

    unsigned long long T;
    if (R > 0) {
        for (int pss = 0; pss < 3; pss++) {
            lh[tid] = 0;
            __syncthreads();
            unsigned pref = scal[0];
            int sh_d = 16 - 8 * pss;
            unsigned pm = 0xFFFFFFFFu << (sh_d + 8);
            for (int i = tid; i < n; i += 256) {
                unsigned a = (unsigned)(cand[i] >> 32);
                if ((a & pm) == (pref & pm))
                    atomicAdd(&lh[(a >> sh_d) & 255u], 1u);
            }
            __syncthreads();
            suf[tid] = lh[tid];
            __syncthreads();
            for (int off = 1; off < 256; off <<= 1) {
                unsigned v = (tid + off < 256) ? suf[tid + off] : 0u;
                __syncthreads();
                suf[tid] += v;
                __syncthreads();
            }
            {
                unsigned Rc = scal[1];
                unsigned hi2 = (tid == 255) ? 0u : suf[tid + 1];
                if (suf[tid] >= Rc && hi2 < Rc) {
                    scal[0] = pref | ((unsigned)tid << sh_d);
                    scal[1] = Rc - hi2;
                }
            }
            __syncthreads();
        }
        unsigned Ta = scal[0];
        unsigned Rrem = scal[1];
        for (int i = tid; i < n; i += 256) {
            unsigned long long kv = cand[i];
            if ((unsigned)(kv >> 32) == Ta) {
                unsigned pos = atomicAdd(&scal[2], 1u);
                if (pos < 8192u) s_tie[pos] = (unsigned)(kv & 0xFFFFFFFFull);
            }
        }
        __syncthreads();
        unsigned Cq = scal[2]; if (Cq > 8192u) Cq = 8192u;
        if (Rrem >= 1u && Rrem < Cq) {
            for (int i = tid; i < (int)Cq; i += 256) {
                unsigned me = s_tie[i];
                unsigned r = 0;
                for (int j = 0; j < (int)Cq; j++) r += (s_tie[j] > me) ? 1u : 0u;
                if (r == Rrem - 1u) scal[3] = me;
            }
        }
        __syncthreads();
        T = ((unsigned long long)Ta << 32) | (unsigned long long)scal[3];
    } else {
        T = ~0ull;
    }
    if (tid == 0) st->prefix = T;
}

// ---- stage 9b: grid-wide virtual-edge emit ----
__device__ void st9b_emit(const P& p)
{
    RState* st = (RState*)(p.ws + OFF_STATE);
    const unsigned long long* cand = (const unsigned long long*)(p.ws + OFF_CAND);
    int* src_all = (int*)(p.ws + OFF_SRCA);
    int* dst_all = (int*)(p.ws + OFF_DSTA);
    float* mask_all = (float*)(p.ws + OFF_MASKA);
    int n = (int)st->cand_count;
    unsigned long long T = st->prefix;
    int lane = threadIdx.x & 63;
    for (int i0 = blockIdx.x * 256; i0 < n; i0 += GRID_ * 256) {
        int i = i0 + threadIdx.x;
        bool sel = (i < n) && (cand[i] >= T);
        unsigned long long b = __ballot(sel);
        int wc = __popcll(b);
        int basep = 0;
        if (lane == 0 && wc) basep = (int)atomicAdd(&st->sel_count, (unsigned)wc);
        basep = __shfl(basep, 0);
        if (sel) {
            int slot = basep + __popcll(b & ((1ull << lane) - 1ull));
            if (slot < EV_) {
                unsigned flat = 0xFFFFFFFFu - (unsigned)(cand[i] & 0xFFFFFFFFull);
                src_all[E_ + slot] = (int)(flat / (unsigned)K_);
                dst_all[E_ + slot] = (int)(flat % (unsigned)K_);
                mask_all[E_ + slot] = 1.0f;
            }
        }
    }
}

// ---- stage 12: final mixing + pos copy ----
__device__ void st12_final(const P& p)
{
    const float* h_local = (const float*)(p.ws + OFF_HLOCAL);
    const int* node2m = (const int*)(p.ws + OFF_N2M);
    const float* aggm = (const float*)(p.ws + OFF_AGGM);
    const float* degm = (const float*)(p.ws + OFF_DEGM);
    const float* h_m = (const float*)(p.ws + OFF_HM);
    for (int idx = blockIdx.x * 256 + threadIdx.x; idx < N_ * C_; idx += GRID_ * 256) {
        if (idx < N_ * 3) p.out_pos[idx] = p.pos[idx];
        int i = idx >> 6, c = idx & 63;
        float mval = p.out_m[i];
        int mi = node2m[i];
        float hh = 0.0f;
        if (mi >= 0) hh = aggm[mi*64 + c] / fmaxf(degm[mi], 1.0f) + h_m[mi*64 + c];
        p.out_h[idx] = (1.0f - mval) * h_local[idx] + mval * hh;
    }
}

// ================= cooperative mega-kernel =================
__global__ __launch_bounds__(256, 3) void k_mega(P p)
{
    cg::grid_group grid = cg::this_grid();
    __shared__ __align__(16) char smem[SMEM_BYTES];
    unsigned int* cnt0 = (unsigned int*)(p.ws + OFF_STATE + 64);
    unsigned int* cnt1 = (unsigned int*)(p.ws + OFF_STATE + 68);
    float* edata = (float*)(p.ws + OFF_CAND);
    float* agg = (float*)(p.ws + OFF_AGG);
    float* deg = (float*)(p.ws + OFF_DEG);
    float* aggm = (float*)(p.ws + OFF_AGGM);
    float* degm = (float*)(p.ws + OFF_DEGM);
    float* h_m = (float*)(p.ws + OFF_HM);
    float* pos_m = (float*)(p.ws + OFF_POSM);
    int* src_all = (int*)(p.ws + OFF_SRCA);
    int* dst_all = (int*)(p.ws + OFF_DSTA);
    float* mask_all = (float*)(p.ws + OFF_MASKA);

    st0_init(p, smem);                                                  grid.sync();
    prep_stage(p, E_, p.eidx, p.eidx + E_, nullptr, p.pos, deg, edata, cnt0);  grid.sync();
    st_conv(p, smem, cnt0, edata, p.h, agg);                            grid.sync();
    st3_hlscore(p);                                                     grid.sync();
    st4_rank(p);                                                        grid.sync();
    st5a_count(p);                                                      grid.sync();
    if (blockIdx.x == 0) st5b_base(p, smem);                            grid.sync();
    st5c_emitmap(p);                                                    grid.sync();
    st6_mastex(p);                                                      grid.sync();
    st7a_attn1(p, smem);                                                grid.sync();
    if (blockIdx.x == 0) st7b_bsel(p, smem);                            grid.sync();
    st8_attn2(p, smem);                                                 grid.sync();
    if (blockIdx.x == 0) st9a_radix(p, smem);                           grid.sync();
    st9b_emit(p);                                                       grid.sync();
    prep_stage(p, EALL_, src_all, dst_all, mask_all, pos_m, degm, edata, cnt1); grid.sync();
    st_conv(p, smem, cnt1, edata, h_m, aggm);                           grid.sync();
    st12_final(p);
}

// ================= fallback wrappers (plain launches, no grid.sync) =================
#define SMEMDECL __shared__ __align__(16) char smem[SMEM_BYTES]
__global__ __launch_bounds__(256, 3) void k_s0(P p) { SMEMDECL; st0_init(p, smem); }
__global__ __launch_bounds__(256, 3) void k_s1(P p) {
    prep_stage(p, E_, p.eidx, p.eidx + E_, nullptr, p.pos,
               (float*)(p.ws + OFF_DEG), (float*)(p.ws + OFF_CAND),
               (unsigned int*)(p.ws + OFF_STATE + 64));
}
__global__ __launch_bounds__(256, 3) void k_s2(P p) {
    SMEMDECL;
    st_conv(p, smem, (const unsigned int*)(p.ws + OFF_STATE + 64),
            (const float*)(p.ws + OFF_CAND), p.h, (float*)(p.ws + OFF_AGG));
}
__global__ __launch_bounds__(256, 3) void k_s3(P p) { st3_hlscore(p); }
__global__ __launch_bounds__(256, 3) void k_s4(P p) { st4_rank(p); }
__global__ __launch_bounds__(256, 3) void k_s5a(P p) { st5a_count(p); }
__global__ __launch_bounds__(256, 3) void k_s5b(P p) { SMEMDECL; if (blockIdx.x == 0) st5b_base(p, smem); }
__global__ __launch_bounds__(256, 3) void k_s5c(P p) { st5c_emitmap(p); }
__global__ __launch_bounds__(256, 3) void k_s6(P p) { st6_mastex(p); }
__global__ __launch_bounds__(256, 3) void k_s7a(P p) { SMEMDECL; st7a_attn1(p, smem); }
__global__ __launch_bounds__(256, 3) void k_s7b(P p) { SMEMDECL; if (blockIdx.x == 0) st7b_bsel(p, smem); }
__global__ __launch_bounds__(256, 3) void k_s8(P p) { SMEMDECL; st8_attn2(p, smem); }
__global__ __launch_bounds__(256, 3) void k_s9a(P p) { SMEMDECL; if (blockIdx.x == 0) st9a_radix(p, smem); }
__global__ __launch_bounds__(256, 3) void k_s9b(P p) { st9b_emit(p); }
__global__ __launch_bounds__(256, 3) void k_s10(P p) {
    prep_stage(p, EALL_, (const int*)(p.ws + OFF_SRCA), (const int*)(p.ws + OFF_DSTA),
               (const float*)(p.ws + OFF_MASKA), (const float*)(p.ws + OFF_POSM),
               (float*)(p.ws + OFF_DEGM), (float*)(p.ws + OFF_CAND),
               (unsigned int*)(p.ws + OFF_STATE + 68));
}
__global__ __launch_bounds__(256, 3) void k_s11(P p) {
    SMEMDECL;
    st_conv(p, smem, (const unsigned int*)(p.ws + OFF_STATE + 68),
            (const float*)(p.ws + OFF_CAND), (const float*)(p.ws + OFF_HM),
            (float*)(p.ws + OFF_AGGM));
}
__global__ __launch_bounds__(256, 3) void k_s12(P p) { st12_final(p); }

// ================= launch =================
extern "C" void kernel_launch(void* const* d_in, const int* in_sizes, int n_in,
                              void* d_out, int out_size, void* d_ws, size_t ws_size,
                              hipStream_t stream)
{
    (void)in_sizes; (void)n_in; (void)out_size; (void)ws_size;
    P p;
    p.h     = (const float*)d_in[0];
    p.pos   = (const float*)d_in[1];
    p.eidx  = (const int*)d_in[2];
    p.fc_w1 = (const float*)d_in[3];
    p.fc_b1 = (const float*)d_in[4];
    p.fc_w2 = (const float*)d_in[5];
    p.fc_b2 = (const float*)d_in[6];
    p.lin_w = (const float*)d_in[7];
    p.ms_w1 = (const float*)d_in[8];
    p.ms_b1 = (const float*)d_in[9];
    p.ms_w2 = (const float*)d_in[10];
    p.ms_b2 = (const float*)d_in[11];
    p.vg_wq = (const float*)d_in[12];
    p.vg_wk = (const float*)d_in[13];
    p.ws    = (char*)d_ws;
    p.out_h   = (float*)d_out;
    p.out_pos = p.out_h + (size_t)N_ * C_;
    p.out_av  = p.out_pos + (size_t)N_ * 3;
    p.out_m   = p.out_av + (size_t)K_ * K_;

    void* args[] = { &p };
    hipError_t err = hipLaunchCooperativeKernel((const void*)k_mega, dim3(GRID_), dim3(256),
                                                args, 0, stream);
    if (err != hipSuccess) {
        (void)hipGetLastError();   // clear error state; use fallback multi-kernel path
        k_s0 <<<GRID_, 256, 0, stream>>>(p);
        k_s1 <<<GRID_, 256, 0, stream>>>(p);
        k_s2 <<<GRID_, 256, 0, stream>>>(p);
        k_s3 <<<GRID_, 256, 0, stream>>>(p);
        k_s4 <<<GRID_, 256, 0, stream>>>(p);
        k_s5a<<<GRID_, 256, 0, stream>>>(p);
        k_s5b<<<GRID_, 256, 0, stream>>>(p);
        k_s5c<<<GRID_, 256, 0, stream>>>(p);
        k_s6 <<<GRID_, 256, 0, stream>>>(p);
        k_s7a<<<GRID_, 256, 0, stream>>>(p);
        k_s7b<<<GRID_, 256, 0, stream>>>(p);
        k_s8 <<<GRID_, 256, 0, stream>>>(p);
        k_s9a<<<GRID_, 256, 0, stream>>>(p);
        k_s9b<<<GRID_, 256, 0, stream>>>(p);
        k_s10<<<GRID_, 256, 0, stream>>>(p);
        k_s11<<<GRID_, 256, 0, stream>>>(p);
        k_s12<<<GRID_, 256, 0, stream>>>(p);
    }
}

// Round 10
// 737.807 us; speedup vs baseline: 2.8621x; 2.8621x over previous
//
#include <hip/hip_runtime.h>
#include <stdint.h>

// ---------------- problem constants ----------------
constexpr int N_   = 20000;
constexpr int E_   = 160000;
constexpr int C_   = 64;
constexpr int K_   = 2000;
constexpr int EV_  = 32000;
constexpr int EALL_ = E_ + EV_;          // 192000
constexpr int CSH_ = 576;                // C*SH
constexpr int TB_  = 64;                 // edges per block in batched conv

// ---------------- workspace layout (bytes) ----------------
// [ zero block: one memset covers OFF_AGG .. OFF_STATE+256 ]
constexpr size_t OFF_AGG    = 0;                  // N*C f32
constexpr size_t OFF_DEG    = 5120000;            // N f32
constexpr size_t OFF_AGGM   = 5200000;            // K*C f32
constexpr size_t OFF_DEGM   = 5712000;            // K f32
constexpr size_t OFF_RANK   = 5720000;            // N i32
constexpr size_t OFF_MASKA  = 5800000;            // EALL f32
constexpr size_t OFF_EXIST  = 6568000;            // K*K u8
constexpr size_t OFF_HIST   = 10568000;           // 1024 u32
constexpr size_t OFF_STATE  = 10572096;           // RState + counters 256
constexpr size_t ZERO_BYTES = 10572352;
// [ non-zero region ]
constexpr size_t OFF_HLOCAL = 10572352;           // N*C f32
constexpr size_t OFF_KEY    = 15692352;           // N u64
constexpr size_t OFF_SCORE  = 15852352;           // N f32
constexpr size_t OFF_N2M    = 15932352;           // N i32
constexpr size_t OFF_MIDX   = 16012352;           // K i32
constexpr size_t OFF_HM     = 16020352;           // K*C f32
constexpr size_t OFF_POSM   = 16532352;           // K*3 f32
constexpr size_t OFF_Q      = 16556352;           // K*16 f32
constexpr size_t OFF_KBUF   = 16684352;           // K*16 f32
constexpr size_t OFF_SRCA   = 16812352;           // EALL i32
constexpr size_t OFF_DSTA   = 17580352;           // EALL i32
constexpr size_t OFF_TMAX   = 18348352;           // 15625 f32 (+pad)
constexpr size_t OFF_CAND   = 18410880;           // 32 MB: cand keys / edata overlay
// total ~50.4 MB

struct RState {
    unsigned long long prefix;
    int R;
    unsigned int cand_count;
    unsigned int sel_count;
    int bin_thresh;
    unsigned int total;
    unsigned int pad;
};
// state area: RState at +0, cnt0 at +64, cnt1 at +68, w0nz at +72, done_ctr at +76

// ---------------- w0nz: does the edge-independent weight (env==0 path) vanish? ----------------
__global__ void k_w0(const float* __restrict__ fc_b1, const float* __restrict__ fc_w2,
                     const float* __restrict__ fc_b2, int* __restrict__ w0nz)
{
    __shared__ float hid0[64];
    __shared__ int nz;
    int tid = threadIdx.x;
    if (tid == 0) nz = 0;
    if (tid < 64) hid0[tid] = fmaxf(fc_b1[tid], 0.0f);
    __syncthreads();
    if (tid < CSH_) {
        float acc = fc_b2[tid];
        for (int k = 0; k < 64; k++) acc += hid0[k] * fc_w2[k * CSH_ + tid];
        if (acc != 0.0f) atomicOr(&nz, 1);
    }
    __syncthreads();
    if (tid == 0) *w0nz = nz;
}

// ---------------- edge prep: geometry + bessel, deg atomics, compact contributing edges ----------------
// edata layout per edge (20 f32): ef[8], sh[9], src(bits), dst(bits), msk
__global__ __launch_bounds__(256) void k_prep(
    int n_edges, const int* __restrict__ src, const int* __restrict__ dst,
    const float* __restrict__ mask, const float* __restrict__ posn,
    const int* __restrict__ w0nz, float* __restrict__ deg,
    float* __restrict__ edata, unsigned int* __restrict__ cnt)
{
    int e = blockIdx.x * 256 + threadIdx.x;
    bool valid = e < n_edges;
    int s_i = 0, d_i = 0; float msk = 0.0f;
    if (valid) {
        msk = mask ? mask[e] : 1.0f;
        if (msk != 0.0f) { s_i = src[e]; d_i = dst[e]; }
    }
    bool active = valid && (msk != 0.0f);

    float vx = 0.f, vy = 0.f, vz = 0.f;
    if (active) {
        vx = posn[s_i*3+0] - posn[d_i*3+0];
        vy = posn[s_i*3+1] - posn[d_i*3+1];
        vz = posn[s_i*3+2] - posn[d_i*3+2];
    }
    float r = sqrtf(vx*vx + vy*vy + vz*vz + 1e-12f);
    float invr = 1.0f / r;
    float x = vx*invr, y = vy*invr, z = vz*invr;
    const float s3 = 1.7320508075688772f, s15 = 3.872983346207417f, s5 = 2.23606797749979f;
    float sh[9];
    sh[0] = 1.0f; sh[1] = s3*x; sh[2] = s3*y; sh[3] = s3*z;
    sh[4] = s15*x*y; sh[5] = s15*y*z; sh[6] = 0.5f*s5*(3.0f*z*z - 1.0f);
    sh[7] = s15*x*z; sh[8] = 0.5f*s15*(x*x - y*y);

    float u = r * 0.2f; u = u > 1.0f ? 1.0f : u;
    float u2 = u*u, u6 = u2*u2*u2, u7 = u6*u, u8 = u7*u;
    float env = 1.0f - 28.0f*u6 + 48.0f*u7 - 21.0f*u8;
    float rc = r > 1e-9f ? r : 1e-9f;
    const float bpref = 0.6324555320336759f;      // sqrt(2/5)
    const float PIov5 = 0.6283185307179586f;
    float ef[8];
    #pragma unroll
    for (int n = 0; n < 8; n++)
        ef[n] = bpref * sinf(PIov5 * r * (float)(n + 1)) / rc * env;

    if (active) atomicAdd(&deg[s_i], msk);

    bool contrib = active && !((env == 0.0f) && (*w0nz == 0));
    int lane = threadIdx.x & 63;
    unsigned long long b = __ballot(contrib);
    int wc = __popcll(b);
    int base = 0;
    if (lane == 0 && wc) base = (int)atomicAdd(cnt, (unsigned)wc);
    base = __shfl(base, 0);
    if (contrib) {
        int slot = base + __popcll(b & ((1ull << lane) - 1ull));
        float* p = edata + (size_t)slot * 20;
        #pragma unroll
        for (int n = 0; n < 8; n++) p[n] = ef[n];
        #pragma unroll
        for (int t = 0; t < 9; t++) p[8+t] = sh[t];
        p[17] = __int_as_float(s_i);
        p[18] = __int_as_float(d_i);
        p[19] = msk;
    }
}

// ---------------- batched conv GEMM: 64 edges/block, thread = 4 edges x 4 outputs ----------------
// Both GEMM operands arrive as b128 LDS reads (hid stored [k][e], tp stored [j_local][e] stride 68).
// LDS: misc 3072 + hid 16384 + tp 17408 + w 16384 = 53248 B -> 3 blocks/CU
__global__ __launch_bounds__(256, 3) void k_convg(
    const unsigned int* __restrict__ cnt, const float* __restrict__ edata,
    const float* __restrict__ hn,
    const float* __restrict__ fc_w1, const float* __restrict__ fc_b1,
    const float* __restrict__ fc_w2, const float* __restrict__ fc_b2,
    const float* __restrict__ lin_w, float* __restrict__ agg)
{
    __shared__ float s_misc[TB_ * 12];                 // sh[9], src, msk, dst
    __shared__ __align__(16) float s_hid[64 * 64];     // [k][e]
    __shared__ __align__(16) float s_tp[64 * 68];      // [j_local][e], row stride 68
    __shared__ __align__(16) float s_w[4096];          // w2 chunk, then lin_w chunk

    const int tid = threadIdx.x;
    const int oq = (tid & 15) * 4;                     // output/j quad (chunk-local)
    const int e0 = (tid >> 4) * 4;                     // this thread's 4 edges

    const int nheavy = (int)*cnt;
    const int nblk = (nheavy + TB_ - 1) / TB_;

    for (int blk = blockIdx.x; blk < nblk; blk += gridDim.x) {
        const int ebase = blk * TB_;
        int nE = nheavy - ebase; if (nE > TB_) nE = TB_;

        __syncthreads();    // prior tile fully consumed
        for (int idx = tid; idx < TB_ * 12; idx += 256) {
            int e = idx / 12, f = idx - 12 * e;
            float v = 0.0f;
            if (e < nE) {
                const float* p = edata + (size_t)(ebase + e) * 20;
                v = (f < 9) ? p[8 + f] : (f == 9) ? p[17] : (f == 10) ? p[19] : p[18];
            }
            s_misc[idx] = v;
        }
        // hid transposed [k][e]
        for (int idx = tid; idx < TB_ * 64; idx += 256) {
            int k = idx >> 6, e = idx & 63;
            float hv = 0.0f;
            if (e < nE) {
                const float* p = edata + (size_t)(ebase + e) * 20;
                float acc = fc_b1[k];
                #pragma unroll
                for (int n = 0; n < 8; n++) acc += p[n] * fc_w1[n * 64 + k];
                hv = fmaxf(acc, 0.0f);
            }
            s_hid[k * 64 + e] = hv;
        }
        float acc[4][4] = {{0,0,0,0},{0,0,0,0},{0,0,0,0},{0,0,0,0}};
        __syncthreads();

        const int d0 = __float_as_int(s_misc[(e0+0) * 12 + 11]);
        const int d1 = __float_as_int(s_misc[(e0+1) * 12 + 11]);
        const int d2 = __float_as_int(s_misc[(e0+2) * 12 + 11]);
        const int d3 = __float_as_int(s_misc[(e0+3) * 12 + 11]);

        for (int cj = 0; cj < 9; cj++) {
            const int j0 = cj * 64;
            if (cj) __syncthreads();           // prev chunk's GEMM2 done with s_w / s_tp
            for (int i4 = tid; i4 < 1024; i4 += 256) {
                int k = i4 >> 4, q4 = (i4 & 15) * 4;
                *reinterpret_cast<float4*>(&s_w[k * 64 + q4]) =
                    *reinterpret_cast<const float4*>(&fc_w2[k * CSH_ + j0 + q4]);
            }
            __syncthreads();

            const int jb = j0 + oq;
            // prefetch h[dst][c] for this chunk (c spans at most 2 values per thread)
            const int c0 = jb / 9, c1 = (jb + 3) / 9;
            float hA0 = hn[d0 * 64 + c0], hB0 = hn[d0 * 64 + c1];
            float hA1 = hn[d1 * 64 + c0], hB1 = hn[d1 * 64 + c1];
            float hA2 = hn[d2 * 64 + c0], hB2 = hn[d2 * 64 + c1];
            float hA3 = hn[d3 * 64 + c0], hB3 = hn[d3 * 64 + c1];

            // GEMM1: a[e][q] = b2 + hid[e][:] @ W2[:, jb+q]; both operands b128
            float a[4][4];
            #pragma unroll
            for (int q = 0; q < 4; q++) {
                float b = fc_b2[jb + q];
                a[0][q]=b; a[1][q]=b; a[2][q]=b; a[3][q]=b;
            }
            #pragma unroll 4
            for (int k = 0; k < 64; k++) {
                float4 w4 = *reinterpret_cast<const float4*>(&s_w[k * 64 + oq]);
                float4 h4 = *reinterpret_cast<const float4*>(&s_hid[k * 64 + e0]);
                a[0][0]+=h4.x*w4.x; a[0][1]+=h4.x*w4.y; a[0][2]+=h4.x*w4.z; a[0][3]+=h4.x*w4.w;
                a[1][0]+=h4.y*w4.x; a[1][1]+=h4.y*w4.y; a[1][2]+=h4.y*w4.z; a[1][3]+=h4.y*w4.w;
                a[2][0]+=h4.z*w4.x; a[2][1]+=h4.z*w4.y; a[2][2]+=h4.z*w4.z; a[2][3]+=h4.z*w4.w;
                a[3][0]+=h4.w*w4.x; a[3][1]+=h4.w*w4.y; a[3][2]+=h4.w*w4.z; a[3][3]+=h4.w*w4.w;
            }
            // tp[j_local][e] = h_dst[e][c] * sh[e][si] * a[e][q]
            // CHUNK-LOCAL row index (oq+q), NOT global j  (R8/R9 crash: used j*68 -> LDS OOB)
            #pragma unroll
            for (int q = 0; q < 4; q++) {
                int j = jb + q; int cc = j / 9; int si = j - 9 * cc;
                float4 tpv;
                tpv.x = (cc == c0 ? hA0 : hB0) * s_misc[(e0+0) * 12 + si] * a[0][q];
                tpv.y = (cc == c0 ? hA1 : hB1) * s_misc[(e0+1) * 12 + si] * a[1][q];
                tpv.z = (cc == c0 ? hA2 : hB2) * s_misc[(e0+2) * 12 + si] * a[2][q];
                tpv.w = (cc == c0 ? hA3 : hB3) * s_misc[(e0+3) * 12 + si] * a[3][q];
                *reinterpret_cast<float4*>(&s_tp[(oq + q) * 68 + e0]) = tpv;
            }
            __syncthreads();                  // tp visible; GEMM1 done with s_w

            for (int i4 = tid; i4 < 1024; i4 += 256) {
                *reinterpret_cast<float4*>(&s_w[i4 * 4]) =
                    *reinterpret_cast<const float4*>(&lin_w[j0 * 64 + i4 * 4]);
            }
            __syncthreads();

            // GEMM2: acc[e][q] += tp[e][:] @ lin_w[:, oq+q]; both operands b128
            #pragma unroll 4
            for (int jj = 0; jj < 64; jj++) {
                float4 l4 = *reinterpret_cast<const float4*>(&s_w[jj * 64 + oq]);
                float4 t4 = *reinterpret_cast<const float4*>(&s_tp[jj * 68 + e0]);
                acc[0][0]+=t4.x*l4.x; acc[0][1]+=t4.x*l4.y; acc[0][2]+=t4.x*l4.z; acc[0][3]+=t4.x*l4.w;
                acc[1][0]+=t4.y*l4.x; acc[1][1]+=t4.y*l4.y; acc[1][2]+=t4.y*l4.z; acc[1][3]+=t4.y*l4.w;
                acc[2][0]+=t4.z*l4.x; acc[2][1]+=t4.z*l4.y; acc[2][2]+=t4.z*l4.z; acc[2][3]+=t4.z*l4.w;
                acc[3][0]+=t4.w*l4.x; acc[3][1]+=t4.w*l4.y; acc[3][2]+=t4.w*l4.z; acc[3][3]+=t4.w*l4.w;
            }
        }

        // emit
        #pragma unroll
        for (int t = 0; t < 4; t++) {
            float mk = s_misc[(e0+t) * 12 + 10];
            if (mk != 0.0f) {
                int s = __float_as_int(s_misc[(e0+t) * 12 + 9]);
                #pragma unroll
                for (int q = 0; q < 4; q++) atomicAdd(&agg[s * 64 + oq + q], acc[t][q] * mk);
            }
        }
    }
}

// ---------------- h_local + score + sort key (merged) ----------------
__global__ __launch_bounds__(256) void k_hlscore(const float* __restrict__ h,
    const float* __restrict__ agg, const float* __restrict__ deg,
    const float* __restrict__ ms_w1, const float* __restrict__ ms_b1,
    const float* __restrict__ ms_w2, const float* __restrict__ ms_b2,
    float* __restrict__ h_local, float* __restrict__ score, unsigned long long* __restrict__ key)
{
    int wid = threadIdx.x >> 6, lane = threadIdx.x & 63;
    int n = blockIdx.x * 4 + wid;
    if (n >= N_) return;
    float d = fmaxf(deg[n], 1.0f);
    float hl = h[n*64 + lane] + agg[n*64 + lane] / d;
    h_local[n*64 + lane] = hl;
    float acc = ms_b1[lane];
    #pragma unroll
    for (int i = 0; i < 16; i++) acc += __shfl(hl, i) * ms_w1[i*64 + lane];
    acc = fmaxf(acc, 0.0f);
    float part = acc * ms_w2[lane];
    #pragma unroll
    for (int off = 32; off > 0; off >>= 1) part += __shfl_xor(part, off);
    if (lane == 0) {
        float s = part + ms_b2[0];
        float sc = 1.0f / (1.0f + expf(-s));
        score[n] = sc;
        key[n] = ((unsigned long long)__float_as_uint(sc) << 32)
               | (unsigned long long)(0xFFFFFFFFu - (unsigned)n);
    }
}

// ---------------- exact top-K rank counting: wave-uniform global reads ----------------
__global__ __launch_bounds__(256) void k_rank(const unsigned long long* __restrict__ key,
                                              int* __restrict__ rankcnt)
{
    int i = blockIdx.x * 256 + threadIdx.x;
    int seg = blockIdx.y;
    int lo = seg * 1250, hi = lo + 1250;
    unsigned long long my = (i < N_) ? key[i] : ~0ull;
    int cnt = 0;
    #pragma unroll 8
    for (int j = lo; j < hi; j++) cnt += (key[j] > my) ? 1 : 0;
    if (i < N_ && cnt) atomicAdd(&rankcnt[i], cnt);
}

// ---------------- selection + ordered compaction, chunked coalesced block scan ----------------
__global__ __launch_bounds__(1024) void k_scanfin(const int* __restrict__ rankcnt,
    const float* __restrict__ score, int* __restrict__ node2m, int* __restrict__ midx,
    float* __restrict__ m_out)
{
    __shared__ int wsum[16];
    __shared__ int wbase[16];
    __shared__ int s_base;
    int tid = threadIdx.x, lane = tid & 63, wv = tid >> 6;
    if (tid == 0) s_base = 0;
    __syncthreads();
    for (int c = 0; c < 20; c++) {
        int idx = c * 1024 + tid;
        int sel = 0;
        if (idx < N_) {
            sel = (rankcnt[idx] < K_) ? 1 : 0;
            m_out[idx] = sel ? score[idx] : 0.0f;
        }
        int v = sel;
        #pragma unroll
        for (int off = 1; off < 64; off <<= 1) {
            int u = __shfl_up(v, off);
            if (lane >= off) v += u;
        }
        if (lane == 63) wsum[wv] = v;
        __syncthreads();
        if (tid == 0) {
            int runb = s_base;
            for (int w = 0; w < 16; w++) { wbase[w] = runb; runb += wsum[w]; }
            s_base = runb;
        }
        __syncthreads();
        if (idx < N_) {
            if (sel) { int rk = wbase[wv] + v - 1; node2m[idx] = rk; midx[rk] = idx; }
            else node2m[idx] = -1;
        }
    }
}

// ---------------- master gather + q/k proj + exist matrix (merged) ----------------
__global__ __launch_bounds__(256) void k_mastex(const int* __restrict__ midx,
    const float* __restrict__ h_local, const float* __restrict__ pos,
    const float* __restrict__ vg_wq, const float* __restrict__ vg_wk,
    const int* __restrict__ src, const int* __restrict__ dst, const int* __restrict__ node2m,
    float* __restrict__ h_m, float* __restrict__ pos_m,
    float* __restrict__ qbuf, float* __restrict__ kbuf,
    int* __restrict__ src_all, int* __restrict__ dst_all,
    float* __restrict__ mask_all, unsigned char* __restrict__ exist)
{
    int b = blockIdx.x;
    if (b < 500) {
        int mi = b * 4 + (threadIdx.x >> 6);
        int lane = threadIdx.x & 63;
        int node = midx[mi];
        h_m[mi*64 + lane] = h_local[node*64 + lane];
        if (lane < 3) pos_m[mi*3 + lane] = pos[node*3 + lane];
        if (lane < 32) {
            int j = lane & 15;
            const float* wm = (lane < 16) ? vg_wq : vg_wk;
            float acc = 0.0f;
            #pragma unroll
            for (int i = 0; i < 16; i++) acc += h_local[node*64 + i] * wm[i*16 + j];
            if (lane < 16) qbuf[mi*16 + j] = acc; else kbuf[mi*16 + j] = acc;
        }
    } else {
        int e = (b - 500) * 256 + threadIdx.x;   // covers exactly E_
        int sm = node2m[src[e]], dm = node2m[dst[e]];
        bool em = (sm >= 0) && (dm >= 0);
        int smc = sm >= 0 ? sm : 0;
        int dmc = dm >= 0 ? dm : 0;
        src_all[e] = smc; dst_all[e] = dmc; mask_all[e] = em ? 1.0f : 0.0f;
        if (em) exist[smc * K_ + dmc] = 1;
    }
}

// ---------------- attention pass 1: Av + tile max + histogram + fused bin-threshold pick ----------------
constexpr int NTILE_ = (K_ / 16) * (K_ / 16);   // 15625
__global__ __launch_bounds__(256) void k_attn1(const float* __restrict__ qbuf,
    const float* __restrict__ kbuf, const unsigned char* __restrict__ exist,
    float* __restrict__ Av, float* __restrict__ tmax, unsigned int* __restrict__ hist,
    RState* st, unsigned int* __restrict__ done_ctr)
{
    constexpr int TBK = K_ / 16;
    __shared__ float sq[16][17], sk[16][17];
    __shared__ unsigned int lh[1024];
    __shared__ float wmax[4];
    __shared__ unsigned int ha[1024], hb[1024];
    __shared__ unsigned int s_last;
    int tid = threadIdx.x;
    for (int b = tid; b < 1024; b += 256) lh[b] = 0;

    for (int t = blockIdx.x; t < NTILE_; t += gridDim.x) {
        int bi = t / TBK, bj = t % TBK;
        int i0 = bi * 16, j0 = bj * 16;
        int r = tid >> 4, c = tid & 15;
        __syncthreads();
        sq[r][c] = qbuf[(i0 + r) * 16 + c];
        sk[r][c] = kbuf[(j0 + r) * 16 + c];
        __syncthreads();
        int ti = tid >> 4, tj = tid & 15;
        float dot = 0.0f;
        #pragma unroll
        for (int cc = 0; cc < 16; cc++) dot += sq[ti][cc] * sk[tj][cc];
        float attn = 1.0f / (1.0f + expf(-dot * 0.25f));
        int gi = i0 + ti, gj = j0 + tj;
        int flat = gi * K_ + gj;
        bool ex = (exist[flat] != 0) || (gi == gj);
        bool av = (!ex) && (attn > 0.5f);
        Av[flat] = av ? 1.0f : 0.0f;
        float cv = av ? attn : 0.0f;
        if (av) {
            unsigned bin = (__float_as_uint(attn) - 0x3F000000u) >> 13;
            if (bin > 1023u) bin = 1023u;
            atomicAdd(&lh[bin], 1u);
        }
        float wm = cv;
        #pragma unroll
        for (int off = 32; off > 0; off >>= 1) wm = fmaxf(wm, __shfl_xor(wm, off));
        int wid = tid >> 6, lane = tid & 63;
        if (lane == 0) wmax[wid] = wm;
        __syncthreads();
        if (tid == 0) tmax[t] = fmaxf(fmaxf(wmax[0], wmax[1]), fmaxf(wmax[2], wmax[3]));
    }
    __syncthreads();
    for (int b = tid; b < 1024; b += 256) {
        unsigned v = lh[b];
        if (v) atomicAdd(&hist[b], v);
    }
    __syncthreads();
    __threadfence();
    if (tid == 0) s_last = (atomicAdd(done_ctr, 1u) == (unsigned)gridDim.x - 1u) ? 1u : 0u;
    __syncthreads();
    if (!s_last) return;
    __threadfence();
    for (int b = tid; b < 1024; b += 256) ha[b] = hist[b];
    __syncthreads();
    unsigned* srcp = ha; unsigned* dstp = hb;
    for (int off = 1; off < 1024; off <<= 1) {
        for (int b = tid; b < 1024; b += 256)
            dstp[b] = srcp[b] + ((b + off < 1024) ? srcp[b + off] : 0u);
        __syncthreads();
        unsigned* tmp = srcp; srcp = dstp; dstp = tmp;
    }
    unsigned total = srcp[0];
    int R = (total < (unsigned)EV_) ? (int)total : EV_;
    if (tid == 0) {
        st->R = R; st->total = total; st->cand_count = 0; st->sel_count = 0;
        if (R == 0) st->bin_thresh = 1024;
    }
    __syncthreads();
    if (R > 0) {
        for (int b = tid; b < 1024; b += 256) {
            unsigned hi2 = (b == 1023) ? 0u : srcp[b + 1];
            if ((int)srcp[b] >= R && (int)hi2 < R) st->bin_thresh = b;
        }
    }
}

// ---------------- attention pass 2: store candidate keys above bin threshold ----------------
__global__ __launch_bounds__(256) void k_attn2(const float* __restrict__ qbuf,
    const float* __restrict__ kbuf, const unsigned char* __restrict__ exist,
    const float* __restrict__ tmax, RState* st, unsigned long long* __restrict__ cand)
{
    constexpr int TBK = K_ / 16;
    __shared__ float sq[16][17], sk[16][17];
    __shared__ int wb[4];
    __shared__ int bb;
    int tid = threadIdx.x;
    unsigned tbits = 0x3F000000u + ((unsigned)st->bin_thresh << 13);

    for (int t = blockIdx.x; t < NTILE_; t += gridDim.x) {
        if (__float_as_uint(tmax[t]) < tbits) continue;     // uniform per block
        int bi = t / TBK, bj = t % TBK;
        int i0 = bi * 16, j0 = bj * 16;
        int r = tid >> 4, c = tid & 15;
        __syncthreads();
        sq[r][c] = qbuf[(i0 + r) * 16 + c];
        sk[r][c] = kbuf[(j0 + r) * 16 + c];
        __syncthreads();
        int ti = tid >> 4, tj = tid & 15;
        float dot = 0.0f;
        #pragma unroll
        for (int cc = 0; cc < 16; cc++) dot += sq[ti][cc] * sk[tj][cc];
        float attn = 1.0f / (1.0f + expf(-dot * 0.25f));
        int gi = i0 + ti, gj = j0 + tj;
        int flat = gi * K_ + gj;
        bool ex = (exist[flat] != 0) || (gi == gj);
        bool store = (!ex) && (attn > 0.5f) && (__float_as_uint(attn) >= tbits);

        unsigned long long keyv = ((unsigned long long)__float_as_uint(attn) << 32)
                                | (unsigned long long)(0xFFFFFFFFu - (unsigned)flat);
        int wid = tid >> 6, lane = tid & 63;
        unsigned long long b = __ballot(store);
        int wc = __popcll(b);
        if (lane == 0) wb[wid] = wc;
        __syncthreads();
        if (tid == 0) {
            int s = 0;
            for (int w = 0; w < 4; w++) { int cc2 = wb[w]; wb[w] = s; s += cc2; }
            bb = s ? (int)atomicAdd(&st->cand_count, (unsigned)s) : 0;
        }
        __syncthreads();
        if (store) {
            int slot = bb + wb[wid] + __popcll(b & ((1ull << lane) - 1ull));
            cand[slot] = keyv;
        }
    }
}

// ---------------- radix select: 3 passes over attn bytes + tie resolution + emit ----------------
__global__ __launch_bounds__(1024) void k_radixsel(RState* st,
    const unsigned long long* __restrict__ cand,
    int* __restrict__ src_all, int* __restrict__ dst_all, float* __restrict__ mask_all)
{
    __shared__ unsigned int lh[256];
    __shared__ unsigned int suf[256];
    __shared__ unsigned int s_tie[8192];
    __shared__ unsigned int s_pref, s_R, s_tiecnt, s_cfth;
    int tid = threadIdx.x;
    int n = (int)st->cand_count;
    int R = st->R;
    if (tid == 0) { s_pref = 0x3F000000u; s_R = (unsigned)R; s_tiecnt = 0; s_cfth = 0; }
    __syncthreads();

    unsigned long long T;
    if (R > 0) {
        for (int p = 0; p < 3; p++) {
            if (tid < 256) lh[tid] = 0;
            __syncthreads();
            unsigned pref = s_pref;
            int sh_d = 16 - 8 * p;
            unsigned pm = 0xFFFFFFFFu << (sh_d + 8);
            for (int i = tid; i < n; i += 1024) {
                unsigned a = (unsigned)(cand[i] >> 32);
                if ((a & pm) == (pref & pm))
                    atomicAdd(&lh[(a >> sh_d) & 255u], 1u);
            }
            __syncthreads();
            if (tid < 256) suf[tid] = lh[tid];
            __syncthreads();
            for (int off = 1; off < 256; off <<= 1) {
                unsigned v = 0;
                if (tid < 256 && tid + off < 256) v = suf[tid + off];
                __syncthreads();
                if (tid < 256) suf[tid] += v;
                __syncthreads();
            }
            if (tid < 256) {
                unsigned Rc = s_R;
                unsigned hi2 = (tid == 255) ? 0u : suf[tid + 1];
                if (suf[tid] >= Rc && hi2 < Rc) {
                    s_pref = pref | ((unsigned)tid << sh_d);
                    s_R = Rc - hi2;
                }
            }
            __syncthreads();
        }
        unsigned Ta = s_pref;
        unsigned Rrem = s_R;
        for (int i = tid; i < n; i += 1024) {
            unsigned long long kv = cand[i];
            if ((unsigned)(kv >> 32) == Ta) {
                unsigned pos = atomicAdd(&s_tiecnt, 1u);
                if (pos < 8192u) s_tie[pos] = (unsigned)(kv & 0xFFFFFFFFull);
            }
        }
        __syncthreads();
        unsigned Cq = s_tiecnt; if (Cq > 8192u) Cq = 8192u;
        if (Rrem >= 1u && Rrem < Cq) {
            for (int i = tid; i < (int)Cq; i += 1024) {
                unsigned me = s_tie[i];
                unsigned r = 0;
                for (int j = 0; j < (int)Cq; j++) r += (s_tie[j] > me) ? 1u : 0u;
                if (r == Rrem - 1u) s_cfth = me;
            }
        }
        __syncthreads();
        T = ((unsigned long long)Ta << 32) | (unsigned long long)s_cfth;
    } else {
        T = ~0ull;
    }

    int lane = tid & 63;
    for (int i0 = 0; i0 < n; i0 += 1024) {
        int i = i0 + tid;
        bool sel = (i < n) && (cand[i] >= T);
        unsigned long long b = __ballot(sel);
        int wc = __popcll(b);
        int basep = 0;
        if (lane == 0 && wc) basep = (int)atomicAdd(&st->sel_count, (unsigned)wc);
        basep = __shfl(basep, 0);
        if (sel) {
            int slot = basep + __popcll(b & ((1ull << lane) - 1ull));
            if (slot < EV_) {
                unsigned flat = 0xFFFFFFFFu - (unsigned)(cand[i] & 0xFFFFFFFFull);
                src_all[E_ + slot] = (int)(flat / (unsigned)K_);
                dst_all[E_ + slot] = (int)(flat % (unsigned)K_);
                mask_all[E_ + slot] = 1.0f;
            }
        }
    }
}

// ---------------- final mixing + pos copy (merged) ----------------
__global__ void k_finalpos(const float* __restrict__ h_local, const int* __restrict__ node2m,
    const float* __restrict__ aggm, const float* __restrict__ degm, const float* __restrict__ h_m,
    const float* __restrict__ m_out, const float* __restrict__ pos,
    float* __restrict__ out_h, float* __restrict__ out_pos)
{
    int idx = blockIdx.x * 256 + threadIdx.x;
    if (idx < N_ * 3) out_pos[idx] = pos[idx];
    if (idx >= N_ * C_) return;
    int i = idx >> 6, c = idx & 63;
    float mval = m_out[i];
    int mi = node2m[i];
    float hh = 0.0f;
    if (mi >= 0) hh = aggm[mi*64 + c] / fmaxf(degm[mi], 1.0f) + h_m[mi*64 + c];
    out_h[idx] = (1.0f - mval) * h_local[idx] + mval * hh;
}

// ---------------- launch ----------------
extern "C" void kernel_launch(void* const* d_in, const int* in_sizes, int n_in,
                              void* d_out, int out_size, void* d_ws, size_t ws_size,
                              hipStream_t stream)
{
    (void)in_sizes; (void)n_in; (void)out_size; (void)ws_size;
    const float* h     = (const float*)d_in[0];
    const float* pos   = (const float*)d_in[1];
    const int*   eidx  = (const int*)d_in[2];
    const float* fc_w1 = (const float*)d_in[3];
    const float* fc_b1 = (const float*)d_in[4];
    const float* fc_w2 = (const float*)d_in[5];
    const float* fc_b2 = (const float*)d_in[6];
    const float* lin_w = (const float*)d_in[7];
    const float* ms_w1 = (const float*)d_in[8];
    const float* ms_b1 = (const float*)d_in[9];
    const float* ms_w2 = (const float*)d_in[10];
    const float* ms_b2 = (const float*)d_in[11];
    const float* vg_wq = (const float*)d_in[12];
    const float* vg_wk = (const float*)d_in[13];

    char* ws = (char*)d_ws;
    float* agg     = (float*)(ws + OFF_AGG);
    float* deg     = (float*)(ws + OFF_DEG);
    float* aggm    = (float*)(ws + OFF_AGGM);
    float* degm    = (float*)(ws + OFF_DEGM);
    int*   rankcnt = (int*)(ws + OFF_RANK);
    float* mask_all = (float*)(ws + OFF_MASKA);
    unsigned char* exist = (unsigned char*)(ws + OFF_EXIST);
    unsigned int* hist = (unsigned int*)(ws + OFF_HIST);
    RState* st     = (RState*)(ws + OFF_STATE);
    unsigned int* cnt0 = (unsigned int*)(ws + OFF_STATE + 64);
    unsigned int* cnt1 = (unsigned int*)(ws + OFF_STATE + 68);
    int*   w0nz    = (int*)(ws + OFF_STATE + 72);
    unsigned int* done_a1 = (unsigned int*)(ws + OFF_STATE + 76);
    float* h_local = (float*)(ws + OFF_HLOCAL);
    unsigned long long* key = (unsigned long long*)(ws + OFF_KEY);
    float* score   = (float*)(ws + OFF_SCORE);
    int*   node2m  = (int*)(ws + OFF_N2M);
    int*   midx    = (int*)(ws + OFF_MIDX);
    float* h_m     = (float*)(ws + OFF_HM);
    float* pos_m   = (float*)(ws + OFF_POSM);
    float* qbuf    = (float*)(ws + OFF_Q);
    float* kbuf    = (float*)(ws + OFF_KBUF);
    int*   src_all = (int*)(ws + OFF_SRCA);
    int*   dst_all = (int*)(ws + OFF_DSTA);
    float* tmax    = (float*)(ws + OFF_TMAX);
    unsigned long long* cand = (unsigned long long*)(ws + OFF_CAND);
    float* edata   = (float*)(ws + OFF_CAND);        // overlays cand (stream-ordered: safe)

    float* out_h   = (float*)d_out;
    float* out_pos = out_h + (size_t)N_ * C_;
    float* out_av  = out_pos + (size_t)N_ * 3;
    float* out_m   = out_av + (size_t)K_ * K_;

    // single contiguous zero-init
    hipMemsetAsync(ws, 0, ZERO_BYTES, stream);

    k_w0<<<1, 576, 0, stream>>>(fc_b1, fc_w2, fc_b2, w0nz);

    // ---- conv 1 on full graph ----
    k_prep<<<E_ / 256, 256, 0, stream>>>(E_, eidx, eidx + E_, nullptr, pos, w0nz, deg, edata, cnt0);
    k_convg<<<768, 256, 0, stream>>>(cnt0, edata, h, fc_w1, fc_b1, fc_w2, fc_b2, lin_w, agg);

    k_hlscore<<<(N_ + 3) / 4, 256, 0, stream>>>(h, agg, deg, ms_w1, ms_b1, ms_w2, ms_b2,
                                                h_local, score, key);

    k_rank<<<dim3((N_ + 255) / 256, 16), 256, 0, stream>>>(key, rankcnt);
    k_scanfin<<<1, 1024, 0, stream>>>(rankcnt, score, node2m, midx, out_m);

    k_mastex<<<500 + E_ / 256, 256, 0, stream>>>(midx, h_local, pos, vg_wq, vg_wk,
        eidx, eidx + E_, node2m, h_m, pos_m, qbuf, kbuf, src_all, dst_all, mask_all, exist);

    // ---- virtual edge selection ----
    k_attn1<<<1024, 256, 0, stream>>>(qbuf, kbuf, exist, out_av, tmax, hist, st, done_a1);
    k_attn2<<<1024, 256, 0, stream>>>(qbuf, kbuf, exist, tmax, st, cand);
    k_radixsel<<<1, 1024, 0, stream>>>(st, cand, src_all, dst_all, mask_all);

    // ---- conv 2 on master graph ----
    k_prep<<<EALL_ / 256, 256, 0, stream>>>(EALL_, src_all, dst_all, mask_all, pos_m, w0nz,
                                            degm, edata, cnt1);
    k_convg<<<768, 256, 0, stream>>>(cnt1, edata, h_m, fc_w1, fc_b1, fc_w2, fc_b2, lin_w, aggm);

    k_finalpos<<<(N_ * C_ + 255) / 256, 256, 0, stream>>>(h_local, node2m, aggm, degm, h_m,
                                                          out_m, pos, out_h, out_pos);
}